// Round 6
// baseline (225.348 us; speedup 1.0000x reference)
//
#include <hip/hip_runtime.h>

#ifndef KE_CONST
#define KE_CONST 14.3996f
#endif

constexpr float R_MAX_C = 6.0f;
constexpr float LOG2E = 1.4426950408889634f;
constexpr float LN2 = 0.6931471805599453f;

typedef int vint4 __attribute__((ext_vector_type(4)));

// ---- raw-hardware transcendentals (no libm names -> no glibc clash) ----
__device__ __forceinline__ float fast_exp2(float x) { return __builtin_amdgcn_exp2f(x); }
__device__ __forceinline__ float fast_log2(float x) { return __builtin_amdgcn_logf(x); }
__device__ __forceinline__ float fast_exp(float x) { return __builtin_amdgcn_exp2f(x * LOG2E); }
// v_cos_f32: D = cos(S0 * 2*pi) (input in revolutions)
__device__ __forceinline__ float cos_rev(float rev) { return __builtin_amdgcn_cosf(rev); }
__device__ __forceinline__ float fast_sqrt(float x) { return __builtin_amdgcn_sqrtf(x); }
__device__ __forceinline__ float fast_rcp(float x) { return __builtin_amdgcn_rcpf(x); }

__device__ __forceinline__ float softplus_f(float x) {
    return LN2 * fast_log2(1.0f + fast_exp(x));
}

// Pack per-atom record {x,y,z,Zf} -> one aligned 16B gather; also init out=0
// (d_out is re-poisoned to 0xAA before every timed launch).
__global__ void pack_atoms_kernel(const float* __restrict__ R,
                                  const int* __restrict__ Z,
                                  float4* __restrict__ atoms, int n,
                                  float* __restrict__ out) {
    int t = blockIdx.x * blockDim.x + threadIdx.x;
    if (t == 0) out[0] = 0.0f;
    if (t < n) {
        atoms[t] = make_float4(R[3 * t + 0], R[3 * t + 1], R[3 * t + 2],
                               (float)Z[t]);
    }
}

struct EdgeParams {
    float inv_an, c0, c1, c2, c3, e0, e1, e2, e3;
};

// zpow_lut[z] = z^ae from LDS (random idx in [1,50): minor bank aliasing)
__device__ __forceinline__ float edge_term(const float4& ai, const float4& aj,
                                           const EdgeParams& p,
                                           const float* __restrict__ zpow_lut) {
    float dx = aj.x - ai.x, dy = aj.y - ai.y, dz = aj.z - ai.z;
    float dr = fast_sqrt(dx * dx + dy * dy + dz * dz);
    dr = fminf(fmaxf(dr, 0.02f), R_MAX_C);
    // cos(pi*dr/6) = v_cos(dr/12 revolutions)
    float cc = 0.5f * (cos_rev(dr * (1.0f / 12.0f)) + 1.0f);
    float zpi = zpow_lut[(int)ai.w];
    float zpj = zpow_lut[(int)aj.w];
    float dist = dr * (zpi + zpj) * p.inv_an;
    float f = p.c0 * fast_exp(-p.e0 * dist) + p.c1 * fast_exp(-p.e1 * dist) +
              p.c2 * fast_exp(-p.e2 * dist) + p.c3 * fast_exp(-p.e3 * dist);
    return ai.w * aj.w * fast_rcp(dr) * f * cc;
}

// Max-occupancy experiment: 4 edges/thread, __launch_bounds__(256,8)
// -> VGPR<=64 -> 32 waves/CU. MLP carried by wave count (8 waves/SIMD x
// ~4-8 in-flight gathers each = 32-64 outstanding lines/SIMD), instead of
// fighting the compiler for per-wave batching.
__global__ __launch_bounds__(256, 8) void edge_energy_kernel(
    const int* __restrict__ idx,        // [2*E]
    const float4* __restrict__ atoms,   // packed table
    const float* __restrict__ a_exp, const float* __restrict__ a_num,
    const float* __restrict__ coefficients, const float* __restrict__ exponents,
    const float* __restrict__ rep_scale,
    float* __restrict__ out, int nEdges) {
    __shared__ float zpow_lut[64];
    __shared__ float smem[4];

    const float ae = softplus_f(a_exp[0]);
    if (threadIdx.x < 64) {
        float z = (float)(threadIdx.x == 0 ? 1 : threadIdx.x);
        zpow_lut[threadIdx.x] = fast_exp2(ae * fast_log2(z));
    }

    EdgeParams p;
    p.inv_an = fast_rcp(softplus_f(a_num[0]));
    p.c0 = softplus_f(coefficients[0]);
    p.c1 = softplus_f(coefficients[1]);
    p.c2 = softplus_f(coefficients[2]);
    p.c3 = softplus_f(coefficients[3]);
    p.e0 = softplus_f(exponents[0]);
    p.e1 = softplus_f(exponents[1]);
    p.e2 = softplus_f(exponents[2]);
    p.e3 = softplus_f(exponents[3]);
    const float scale = 0.5f * softplus_f(rep_scale[0]) * KE_CONST;
    __syncthreads();

    const long long tid = (long long)blockIdx.x * blockDim.x + threadIdx.x;
    const long long base = tid * 4;

    float acc = 0.0f;
    if (base + 4 <= (long long)nEdges) {
        vint4 ii4 = *(const vint4*)(idx + base);
        vint4 jj4 = *(const vint4*)(idx + nEdges + base);
        int ii[4] = {ii4.x, ii4.y, ii4.z, ii4.w};
        int jj[4] = {jj4.x, jj4.y, jj4.z, jj4.w};
        float4 A[4], B[4];
#pragma unroll
        for (int u = 0; u < 4; ++u) {
            A[u] = atoms[ii[u]];
            B[u] = atoms[jj[u]];
        }
#pragma unroll
        for (int u = 0; u < 4; ++u) {
            float e = edge_term(A[u], B[u], p, zpow_lut);
            acc += (ii[u] != jj[u]) ? e : 0.0f;
        }
    } else if (base < (long long)nEdges) {
        for (long long t = base; t < (long long)nEdges; ++t) {
            int i = idx[t], j = idx[nEdges + t];
            float4 ai = atoms[i];
            float4 aj = atoms[j];
            float e = edge_term(ai, aj, p, zpow_lut);
            acc += (i != j) ? e : 0.0f;
        }
    }

    // wave(64) shuffle reduce -> block -> one atomic
#pragma unroll
    for (int off = 32; off > 0; off >>= 1) acc += __shfl_down(acc, off, 64);
    const int lane = threadIdx.x & 63;
    const int wave = threadIdx.x >> 6;
    if (lane == 0) smem[wave] = acc;
    __syncthreads();
    if (threadIdx.x == 0) {
        float s = (smem[0] + smem[1]) + (smem[2] + smem[3]);
        atomicAdd(out, s * scale);
    }
}

extern "C" void kernel_launch(void* const* d_in, const int* in_sizes, int n_in,
                              void* d_out, int out_size, void* d_ws, size_t ws_size,
                              hipStream_t stream) {
    // setup_inputs order: R, Z, idx, box, offsets, a_exp, a_num, coefficients,
    //                     exponents, rep_scale
    const float* R = (const float*)d_in[0];
    const int* Z = (const int*)d_in[1];
    const int* idx = (const int*)d_in[2];
    const float* a_exp = (const float*)d_in[5];
    const float* a_num = (const float*)d_in[6];
    const float* coefficients = (const float*)d_in[7];
    const float* exponents = (const float*)d_in[8];
    const float* rep_scale = (const float*)d_in[9];

    const int nAtoms = in_sizes[0] / 3;
    const int nEdges = in_sizes[2] / 2;
    float* out = (float*)d_out;

    float4* atoms = (float4*)d_ws;  // needs nAtoms*16 bytes (1.6 MB @ 100k)
    pack_atoms_kernel<<<(nAtoms + 255) / 256, 256, 0, stream>>>(R, Z, atoms,
                                                                nAtoms, out);
    // 4 edges per thread (E = 6.4M -> 6250 blocks of 256)
    const int edges_per_block = 256 * 4;
    const int blocks = (nEdges + edges_per_block - 1) / edges_per_block;
    edge_energy_kernel<<<blocks, 256, 0, stream>>>(
        idx, atoms, a_exp, a_num, coefficients, exponents, rep_scale, out,
        nEdges);
}

// Round 7
// 197.905 us; speedup vs baseline: 1.1387x; 1.1387x over previous
//
#include <hip/hip_runtime.h>

#ifndef KE_CONST
#define KE_CONST 14.3996f
#endif

constexpr float R_MAX_C = 6.0f;
constexpr float LOG2E = 1.4426950408889634f;
constexpr float LN2 = 0.6931471805599453f;

typedef int vint4 __attribute__((ext_vector_type(4)));
typedef float vfloat4 __attribute__((ext_vector_type(4)));

// ---- raw-hardware transcendentals (no libm names -> no glibc clash) ----
__device__ __forceinline__ float fast_exp2(float x) { return __builtin_amdgcn_exp2f(x); }
__device__ __forceinline__ float fast_log2(float x) { return __builtin_amdgcn_logf(x); }
__device__ __forceinline__ float fast_exp(float x) { return __builtin_amdgcn_exp2f(x * LOG2E); }
// v_cos_f32: D = cos(S0 * 2*pi) (input in revolutions)
__device__ __forceinline__ float cos_rev(float rev) { return __builtin_amdgcn_cosf(rev); }
__device__ __forceinline__ float fast_sqrt(float x) { return __builtin_amdgcn_sqrtf(x); }
__device__ __forceinline__ float fast_rcp(float x) { return __builtin_amdgcn_rcpf(x); }

__device__ __forceinline__ float softplus_f(float x) {
    return LN2 * fast_log2(1.0f + fast_exp(x));
}

// Pack per-atom record {x,y,z,Zf} -> one aligned 16B gather; also init out=0
// (d_out is re-poisoned to 0xAA before every timed launch).
__global__ void pack_atoms_kernel(const float* __restrict__ R,
                                  const int* __restrict__ Z,
                                  float4* __restrict__ atoms, int n,
                                  float* __restrict__ out) {
    int t = blockIdx.x * blockDim.x + threadIdx.x;
    if (t == 0) out[0] = 0.0f;
    if (t < n) {
        atoms[t] = make_float4(R[3 * t + 0], R[3 * t + 1], R[3 * t + 2],
                               (float)Z[t]);
    }
}

struct EdgeParams {
    float inv_an, c0, c1, c2, c3, e0, e1, e2, e3;
};

__device__ __forceinline__ float edge_term(const vfloat4& ai, const vfloat4& aj,
                                           const EdgeParams& p,
                                           const float* __restrict__ zpow_lut) {
    float dx = aj.x - ai.x, dy = aj.y - ai.y, dz = aj.z - ai.z;
    float dr = fast_sqrt(dx * dx + dy * dy + dz * dz);
    dr = fminf(fmaxf(dr, 0.02f), R_MAX_C);
    // cos(pi*dr/6) = v_cos(dr/12 revolutions)
    float cc = 0.5f * (cos_rev(dr * (1.0f / 12.0f)) + 1.0f);
    float zpi = zpow_lut[(int)ai.w];
    float zpj = zpow_lut[(int)aj.w];
    float dist = dr * (zpi + zpj) * p.inv_an;
    float f = p.c0 * fast_exp(-p.e0 * dist) + p.c1 * fast_exp(-p.e1 * dist) +
              p.c2 * fast_exp(-p.e2 * dist) + p.c3 * fast_exp(-p.e3 * dist);
    return ai.w * aj.w * fast_rcp(dr) * f * cc;
}

// Forced-issue 16B gather: volatile asm keeps mutual program order and pins
// the destination registers live -> compiler CANNOT sink these into compute.
#define GATHER16(dst, ptr) \
    asm volatile("global_load_dwordx4 %0, %1, off" : "=v"(dst) : "v"(ptr))

// 8 edges/thread; all 16 gathers forced in flight via inline asm, then one
// vmcnt(0) that ties every result register so no use can hoist above it.
__global__ __launch_bounds__(256, 4) void edge_energy_kernel(
    const int* __restrict__ idx,          // [2*E]
    const vfloat4* __restrict__ atoms,    // packed table
    const float* __restrict__ a_exp, const float* __restrict__ a_num,
    const float* __restrict__ coefficients, const float* __restrict__ exponents,
    const float* __restrict__ rep_scale,
    float* __restrict__ out, int nEdges) {
    __shared__ float zpow_lut[64];
    __shared__ float smem[4];

    const float ae = softplus_f(a_exp[0]);
    if (threadIdx.x < 64) {
        float z = (float)(threadIdx.x == 0 ? 1 : threadIdx.x);
        zpow_lut[threadIdx.x] = fast_exp2(ae * fast_log2(z));
    }

    EdgeParams p;
    p.inv_an = fast_rcp(softplus_f(a_num[0]));
    p.c0 = softplus_f(coefficients[0]);
    p.c1 = softplus_f(coefficients[1]);
    p.c2 = softplus_f(coefficients[2]);
    p.c3 = softplus_f(coefficients[3]);
    p.e0 = softplus_f(exponents[0]);
    p.e1 = softplus_f(exponents[1]);
    p.e2 = softplus_f(exponents[2]);
    p.e3 = softplus_f(exponents[3]);
    const float scale = 0.5f * softplus_f(rep_scale[0]) * KE_CONST;
    __syncthreads();

    const long long tid = (long long)blockIdx.x * blockDim.x + threadIdx.x;
    const long long base = tid * 8;

    float acc = 0.0f;
    if (base + 8 <= (long long)nEdges) {
        const vint4* __restrict__ i4 = (const vint4*)(idx) + (base >> 2);
        const vint4* __restrict__ j4 = (const vint4*)(idx + nEdges) + (base >> 2);
        vint4 ia = i4[0];
        vint4 ib = i4[1];
        vint4 ja = j4[0];
        vint4 jb = j4[1];
        int ii[8] = {ia.x, ia.y, ia.z, ia.w, ib.x, ib.y, ib.z, ib.w};
        int jj[8] = {ja.x, ja.y, ja.z, ja.w, jb.x, jb.y, jb.z, jb.w};

        vfloat4 A[8], B[8];
#pragma unroll
        for (int u = 0; u < 8; ++u) {
            GATHER16(A[u], atoms + ii[u]);
            GATHER16(B[u], atoms + jj[u]);
        }
        // Single conservative drain; ties all 16 results so no consumer can
        // be scheduled before the wait (stray compiler loads only make this
        // MORE conservative, never incorrect).
        asm volatile("s_waitcnt vmcnt(0)"
                     : "+v"(A[0]), "+v"(A[1]), "+v"(A[2]), "+v"(A[3]),
                       "+v"(A[4]), "+v"(A[5]), "+v"(A[6]), "+v"(A[7]),
                       "+v"(B[0]), "+v"(B[1]), "+v"(B[2]), "+v"(B[3]),
                       "+v"(B[4]), "+v"(B[5]), "+v"(B[6]), "+v"(B[7])
                     :
                     : "memory");
#pragma unroll
        for (int u = 0; u < 8; ++u) {
            float e = edge_term(A[u], B[u], p, zpow_lut);
            acc += (ii[u] != jj[u]) ? e : 0.0f;
        }
    } else if (base < (long long)nEdges) {
        for (long long t = base; t < (long long)nEdges; ++t) {
            int i = idx[t], j = idx[nEdges + t];
            vfloat4 ai = atoms[i];
            vfloat4 aj = atoms[j];
            float e = edge_term(ai, aj, p, zpow_lut);
            acc += (i != j) ? e : 0.0f;
        }
    }

    // wave(64) shuffle reduce -> block -> one atomic
#pragma unroll
    for (int off = 32; off > 0; off >>= 1) acc += __shfl_down(acc, off, 64);
    const int lane = threadIdx.x & 63;
    const int wave = threadIdx.x >> 6;
    if (lane == 0) smem[wave] = acc;
    __syncthreads();
    if (threadIdx.x == 0) {
        float s = (smem[0] + smem[1]) + (smem[2] + smem[3]);
        atomicAdd(out, s * scale);
    }
}

extern "C" void kernel_launch(void* const* d_in, const int* in_sizes, int n_in,
                              void* d_out, int out_size, void* d_ws, size_t ws_size,
                              hipStream_t stream) {
    // setup_inputs order: R, Z, idx, box, offsets, a_exp, a_num, coefficients,
    //                     exponents, rep_scale
    const float* R = (const float*)d_in[0];
    const int* Z = (const int*)d_in[1];
    const int* idx = (const int*)d_in[2];
    const float* a_exp = (const float*)d_in[5];
    const float* a_num = (const float*)d_in[6];
    const float* coefficients = (const float*)d_in[7];
    const float* exponents = (const float*)d_in[8];
    const float* rep_scale = (const float*)d_in[9];

    const int nAtoms = in_sizes[0] / 3;
    const int nEdges = in_sizes[2] / 2;
    float* out = (float*)d_out;

    float4* atoms = (float4*)d_ws;  // needs nAtoms*16 bytes (1.6 MB @ 100k)
    pack_atoms_kernel<<<(nAtoms + 255) / 256, 256, 0, stream>>>(R, Z, atoms,
                                                                nAtoms, out);
    // 8 edges per thread, exact cover (E = 6.4M -> 3125 blocks of 256)
    const int edges_per_block = 256 * 8;
    const int blocks = (nEdges + edges_per_block - 1) / edges_per_block;
    edge_energy_kernel<<<blocks, 256, 0, stream>>>(
        idx, (const vfloat4*)atoms, a_exp, a_num, coefficients, exponents,
        rep_scale, out, nEdges);
}